// Round 1
// baseline (323.982 us; speedup 1.0000x reference)
//
#include <hip/hip_runtime.h>
#include <math.h>

#define ROWS_PER_BLOCK 8
#define DIM 480          // 128*1 + 64*3 + 32*5
#define NGROUPS 224      // 128 + 64 + 32 groups per row
#define NV4 120          // float4 per row (480/4)
#define BLOCK 256

__global__ __launch_bounds__(BLOCK) void norm_act_kernel(
    const float* __restrict__ in, float* __restrict__ out, int n_rows)
{
    __shared__ float sdata[ROWS_PER_BLOCK * DIM];   // 15360 B
    __shared__ float sscal[ROWS_PER_BLOCK * NGROUPS]; // 7168 B

    const int tid  = threadIdx.x;
    const int row0 = blockIdx.x * ROWS_PER_BLOCK;
    const int rows = min(ROWS_PER_BLOCK, n_rows - row0);
    const int nv4  = rows * NV4;

    const float4* gin  = (const float4*)(in  + (size_t)row0 * DIM);
    float4*       gout = (float4*)      (out + (size_t)row0 * DIM);

    // ---- Pass 1: coalesced float4 global -> LDS staging ----
    for (int v = tid; v < nv4; v += BLOCK) {
        ((float4*)sdata)[v] = gin[v];
    }
    __syncthreads();

    // ---- Pass 2: per-group norm -> sigmoid scaling into LDS ----
    // scaling = silu(max(norm,eps))/max(norm,eps) == sigmoid(max(norm,eps))
    const int ng = rows * NGROUPS;
    for (int g = tid; g < ng; g += BLOCK) {
        const int row = g / NGROUPS;            // constant-divisor magic mul
        const int gi  = g - row * NGROUPS;
        const float* base = sdata + row * DIM;
        float ss;
        if (gi < 128) {                         // 128 x 0e (d=1), offset gi
            const float x = base[gi];
            ss = x * x;
        } else if (gi < 192) {                  // 64 x 1o (d=3), offset 128+3*(gi-128)
            const float* p = base + 128 + (gi - 128) * 3;  // stride 3: conflict-free
            ss = p[0]*p[0] + p[1]*p[1] + p[2]*p[2];
        } else {                                // 32 x 2e (d=5), offset 320+5*(gi-192)
            const float* p = base + 320 + (gi - 192) * 5;  // stride 5: conflict-free
            ss = p[0]*p[0] + p[1]*p[1] + p[2]*p[2] + p[3]*p[3] + p[4]*p[4];
        }
        float n = sqrtf(ss);
        n = fmaxf(n, 1e-8f);
        sscal[row * NGROUPS + gi] = 1.0f / (1.0f + __expf(-n));
    }
    __syncthreads();

    // ---- Pass 3: scale from LDS, coalesced float4 stores ----
    for (int v = tid; v < nv4; v += BLOCK) {
        const int row = v / NV4;
        const int c4  = v - row * NV4;
        const int e0  = c4 * 4;
        float4 x = ((const float4*)sdata)[v];
        const float* sc = sscal + row * NGROUPS;
        float s[4];
        #pragma unroll
        for (int k = 0; k < 4; ++k) {
            const int e = e0 + k;
            int gidx;
            if (e < 128)       gidx = e;                       // region boundaries are
            else if (e < 320)  gidx = 128 + (e - 128) / 3;     // multiples of 4: no
            else               gidx = 192 + (e - 320) / 5;     // divergence inside a f4
            s[k] = sc[gidx];
        }
        x.x *= s[0]; x.y *= s[1]; x.z *= s[2]; x.w *= s[3];
        gout[v] = x;
    }
}

extern "C" void kernel_launch(void* const* d_in, const int* in_sizes, int n_in,
                              void* d_out, int out_size, void* d_ws, size_t ws_size,
                              hipStream_t stream) {
    const float* in  = (const float*)d_in[0];
    float*       out = (float*)d_out;
    const int n_rows = in_sizes[0] / DIM;   // 100000
    const int grid   = (n_rows + ROWS_PER_BLOCK - 1) / ROWS_PER_BLOCK;  // 12500
    norm_act_kernel<<<grid, BLOCK, 0, stream>>>(in, out, n_rows);
}